// Round 15
// baseline (82.634 us; speedup 1.0000x reference)
//
#include <hip/hip_runtime.h>
#include <hip/hip_bf16.h>

#define TT  2048
#define NH  32
#define NKV 8
#define DD  128
#define KVB 128         // keys per LDS tile
#define THR 8.0f        // defer-max rescale threshold (T13)

typedef __attribute__((ext_vector_type(8)))  short  short8;
typedef __attribute__((ext_vector_type(4)))  float  f32x4;
typedef __attribute__((ext_vector_type(16))) float  f32x16;
typedef unsigned int u32;
typedef __attribute__((ext_vector_type(4)))  u32    u32x4;

static __device__ __forceinline__ short f2bf(float x) {
  __bf16 b = (__bf16)x;                 // RNE f32->bf16
  return __builtin_bit_cast(short, b);
}
static __device__ __forceinline__ short8 cvt8(f32x4 a, f32x4 b) {
  short8 r;
  r[0]=f2bf(a[0]); r[1]=f2bf(a[1]); r[2]=f2bf(a[2]); r[3]=f2bf(a[3]);
  r[4]=f2bf(b[0]); r[5]=f2bf(b[1]); r[6]=f2bf(b[2]); r[7]=f2bf(b[3]);
  return r;
}
static __device__ __forceinline__ u32 pk2(float lo, float hi) {
  const u32 a = (u32)(unsigned short)f2bf(lo);
  const u32 b = (u32)(unsigned short)f2bf(hi);
  return a | (b << 16);
}
static __device__ __forceinline__ void gload_lds16(const short* g, short* l) {
  __builtin_amdgcn_global_load_lds(
      (const __attribute__((address_space(1))) u32*)g,
      (__attribute__((address_space(3))) u32*)l, 16, 0, 0);
}

// ---------------- pre-pass: K -> bf16 [kvh][j][d]; V -> bf16 transposed [kvh][d][j] ----
__global__ __launch_bounds__(256) void preconv(
    const float* __restrict__ K, const float* __restrict__ V,
    short* __restrict__ Kbf, short* __restrict__ Vtbf)
{
  const int t = threadIdx.x;
  if (blockIdx.x >= 256) {
    const int b  = blockIdx.x - 256;
    const int rr = (b << 6) + (t >> 2);      // rr = j*8+kvh
    const int q  = t & 3;
    const int j = rr >> 3, kvh = rr & 7;
    const float* src = K + (size_t)rr * DD + q * 32;
    short* dst = Kbf + ((size_t)kvh * TT + j) * DD + q * 32;
#pragma unroll
    for (int i = 0; i < 4; ++i) {
      f32x4 a  = *reinterpret_cast<const f32x4*>(src + i * 8);
      f32x4 bb = *reinterpret_cast<const f32x4*>(src + i * 8 + 4);
      *reinterpret_cast<short8*>(dst + i * 8) = cvt8(a, bb);
    }
  } else {
    const int kvh = blockIdx.x >> 5, jt = blockIdx.x & 31;
    __shared__ short Vl[64][136];
    const int jl = t >> 2, q = t & 3;
    const float* src = V + ((size_t)(jt * 64 + jl) * NKV + kvh) * DD + q * 32;
#pragma unroll
    for (int i = 0; i < 4; ++i) {
      f32x4 a  = *reinterpret_cast<const f32x4*>(src + i * 8);
      f32x4 bb = *reinterpret_cast<const f32x4*>(src + i * 8 + 4);
      *reinterpret_cast<short8*>(&Vl[jl][q * 32 + i * 8]) = cvt8(a, bb);
    }
    __syncthreads();
    const int d = t >> 1, jh = t & 1;
    short8 o[4];
#pragma unroll
    for (int k = 0; k < 4; ++k)
#pragma unroll
      for (int i = 0; i < 8; ++i)
        o[k][i] = Vl[jh * 32 + k * 8 + i][d];
    short* dst = Vtbf + ((size_t)kvh * DD + d) * TT + jt * 64 + jh * 32;
#pragma unroll
    for (int k = 0; k < 4; ++k)
      *reinterpret_cast<short8*>(dst + k * 8) = o[k];
  }
}

// ---------------- main attention kernel ------------------------------------------
// r14 body (proven 77.6us: KVB=128, 8 waves = 4 heads x 2 key-halves, defer-max,
// DMA after QK^T, sx/mbuf epilogue) with PERFECT STATIC BALANCE:
// grid = 256 = one block per CU (LDS 134KB forces 1 block/CU anyway). Block
// (kvh=bid&7, j=bid>>3) processes TWO COMPLETE strips sequentially: heavy 63-j,
// then light j. Tile identity: ceil((64-j)/4) + ceil((j+1)/4) = 17 for ALL j ->
// every CU does exactly 17 tiles; the r14 two-phase dispatch tail (~8 slots of
// the 25-slot makespan) disappears. No partials, no merges, no inter-block sync
// (the r11/r12 failure modes are structurally absent): each strip writes its
// final O/Mo/Lo directly, exactly like r14. Per-job state re-init; barrier
// between jobs protects smem(mbuf)/sx reuse.
// "Only the last tile can cross the diagonal" holds per strip: 128*(nt-1) <=
// 32*q32 (since nt-1 = floor(q32/4)), so tile nt-2 ends at key <= qbase.
// 16B-chunk XOR swizzle: 256B rows = 16 chunks, phys = logical ^ (row&7),
// pre-applied on the global source address (LDS dest linear), applied on reads.
// MFMA 32x32x16 layouts: A: lane=A[row=l&31][k=8*(l>>5)+i];
// B: B[k=8*(l>>5)+i][col=l&31]; C/D: col=l&31, row=(reg&3)+8*(reg>>2)+4*(l>>5).
__global__ __launch_bounds__(512, 2) void attn_fwd(
    const float* __restrict__ Q, const short* __restrict__ Kbf,
    const short* __restrict__ Vtbf, float* __restrict__ O,
    float* __restrict__ Mo, float* __restrict__ Lo)
{
  __shared__ __align__(16) short smem[2*KVB*DD + 2*DD*KVB];  // 128KB: Kb | Vt
  __shared__ float sx[3][2][4][32];                          // m / tmax / lsum exchange

  short (*Kb)[KVB][DD] = reinterpret_cast<short(*)[KVB][DD]>(&smem[0]);
  short (*Vt)[DD][KVB] = reinterpret_cast<short(*)[DD][KVB]>(&smem[2*KVB*DD]);

  const int bid  = blockIdx.x;
  const int kvh  = bid & (NKV - 1);          // kvh == XCD id under round-robin
  const int j    = bid >> 3;                 // 0..31
  const int wv   = threadIdx.x >> 6;         // 0..7
  const int headq= wv & 3;
  const int kh   = wv >> 2;                  // key half: keys [64kh, 64kh+64) per tile
  const int lane = threadIdx.x & 63;
  const int l31  = lane & 31;
  const int hiK  = lane >> 5;
  const int l7   = lane & 7;
  const int head = kvh * 4 + headq;

  // ---- staging offsets (job-invariant): K rows and V d-rows [16wv, 16wv+16) ----
  int koff[4], voff[4];
#pragma unroll
  for (int t = 0; t < 4; ++t) {
    const int row = 16 * wv + 4 * t + (lane >> 4);
    const int sw  = (lane & 15) ^ (4 * (t & 1) + (lane >> 4));
    koff[t] = row * DD + sw * 8;
    voff[t] = row * TT + sw * 8;
  }

  const short* kB = Kbf + (size_t)kvh * TT * DD;
  const short* vB = Vtbf + (size_t)kvh * DD * TT;

  for (int job = 0; job < 2; ++job) {
    const int q32   = (job == 0) ? (63 - j) : j;   // heavy first, then light
    const int qbase = q32 * 32;
    const int q     = qbase + l31;           // this lane's q-column
    const int ntiles = (q32 + 4) >> 2;       // ceil((qbase+32)/128)

    // ---- Q B-frags: lane holds Q[qbase+l31][ks*16 + 8*hiK + i], ks=0..7 ----
    short8 aq[8];
    {
      const float* qp = Q + ((size_t)q * NH + head) * DD + hiK * 8;
#pragma unroll
      for (int ks = 0; ks < 8; ++ks) {
        const float* p = qp + ks * 16;
        aq[ks] = cvt8(*reinterpret_cast<const f32x4*>(p),
                      *reinterpret_cast<const f32x4*>(p + 4));
      }
    }

    f32x16 acc[4];
#pragma unroll
    for (int i = 0; i < 4; ++i) acc[i] = (f32x16)0.0f;
    float m = -INFINITY, tmaxh = -INFINITY, lsum = 0.0f;

    const short* kgp = kB;
    const short* vgp = vB;

    // ---- prologue: DMA tile 0 into buffer 0 ----
#pragma unroll
    for (int t = 0; t < 4; ++t)
      gload_lds16(kgp + koff[t], &Kb[0][16 * wv + 4 * t][0]);
#pragma unroll
    for (int t = 0; t < 4; ++t)
      gload_lds16(vgp + voff[t], &Vt[0][16 * wv + 4 * t][0]);
    kgp += (size_t)KVB * DD;
    vgp += KVB;

    for (int jt = 0; jt < ntiles; ++jt) {
      const int j0  = jt << 7;
      const int buf = jt & 1;

      __syncthreads();   // drains own DMA (vmcnt0); prev buffer free for overwrite

      // ---- QK^T on this wave's 64-key half: st[kg] over keys kh*64+kg*32+[0,32) ----
      f32x16 st[2];
      st[0] = (f32x16)0.0f; st[1] = (f32x16)0.0f;
      __builtin_amdgcn_s_setprio(1);
#pragma unroll
      for (int kg = 0; kg < 2; ++kg) {
        const short* kr = &Kb[buf][kh * 64 + kg * 32 + l31][0];
#pragma unroll
        for (int ks = 0; ks < 8; ++ks) {
          const int c = ((ks << 1) | hiK) ^ l7;
          short8 kb = *reinterpret_cast<const short8*>(kr + c * 8);
          st[kg] = __builtin_amdgcn_mfma_f32_32x32x16_bf16(kb, aq[ks], st[kg], 0, 0, 0);
        }
      }
      __builtin_amdgcn_s_setprio(0);

      // ---- DMA tile jt+1 into buf^1 (r7/r13-proven placement: after QK^T) ----
      if (jt + 1 < ntiles) {
        const int nb = buf ^ 1;
#pragma unroll
        for (int t = 0; t < 4; ++t)
          gload_lds16(kgp + koff[t], &Kb[nb][16 * wv + 4 * t][0]);
#pragma unroll
        for (int t = 0; t < 4; ++t)
          gload_lds16(vgp + voff[t], &Vt[nb][16 * wv + 4 * t][0]);
        kgp += (size_t)KVB * DD;
        vgp += KVB;
      }

      // ---- causal mask: only the last tile can cross the diagonal ----
      if (jt == ntiles - 1) {
#pragma unroll
        for (int kg = 0; kg < 2; ++kg)
#pragma unroll
          for (int r = 0; r < 16; ++r) {
            const int key = j0 + kh * 64 + kg * 32 + (r & 3) + 8 * (r >> 2) + 4 * hiK;
            if (key > q) st[kg][r] = -1.0e10f;
          }
      }

      // ---- half max (lane-local over 64 keys + lane^32 merge) ----
      float mx = fmaxf(st[0][0], st[1][0]);
#pragma unroll
      for (int r = 1; r < 16; ++r) mx = fmaxf(mx, fmaxf(st[0][r], st[1][r]));
      mx = fmaxf(mx, __shfl_xor(mx, 32, 64));
      tmaxh = fmaxf(tmaxh, mx);

      // ---- defer-max: rescale only when the running max grows by >THR ----
      if (__any(mx > m + THR)) {
        const float mn = fmaxf(m, mx);
        const float sc = __expf(m - mn);
        m = mn;
        lsum *= sc;
#pragma unroll
        for (int r = 0; r < 16; ++r) {
          const float sf = __shfl(sc, (r & 3) + 8 * (r >> 2) + 4 * hiK, 64);
          acc[0][r] *= sf; acc[1][r] *= sf; acc[2][r] *= sf; acc[3][r] *= sf;
        }
      }

      // ---- P = exp(S-m); pack to PV A-frags via lane^32 exchange ----
      short8 pa[4];
#pragma unroll
      for (int kg = 0; kg < 2; ++kg) {
        float e[16];
#pragma unroll
        for (int r = 0; r < 16; ++r) e[r] = __expf(st[kg][r] - m);
        lsum += (((e[0]+e[1])+(e[2]+e[3]))+((e[4]+e[5])+(e[6]+e[7])))
              + (((e[8]+e[9])+(e[10]+e[11]))+((e[12]+e[13])+(e[14]+e[15])));
#pragma unroll
        for (int h2 = 0; h2 < 2; ++h2) {
          const int b = 8 * h2;
          u32 u0 = pk2(e[b+0], e[b+1]);
          u32 u1 = pk2(e[b+2], e[b+3]);
          u32 u2 = pk2(e[b+4], e[b+5]);
          u32 u3 = pk2(e[b+6], e[b+7]);
          u32 sA = hiK ? u0 : u2;
          u32 sB = hiK ? u1 : u3;
          u32 rA = __shfl_xor(sA, 32, 64);
          u32 rB = __shfl_xor(sB, 32, 64);
          u32x4 w4;
          w4[0] = hiK ? rA : u0;
          w4[1] = hiK ? rB : u1;
          w4[2] = hiK ? u2 : rA;
          w4[3] = hiK ? u3 : rB;
          pa[kg * 2 + h2] = __builtin_bit_cast(short8, w4);
        }
      }

      // ---- P @ V over this wave's 4 key-slices of 16 (keys kh*64 + 16pi) ----
      __builtin_amdgcn_s_setprio(1);
#pragma unroll
      for (int dg = 0; dg < 4; ++dg) {
        const short* vr = &Vt[buf][dg * 32 + l31][0];
#pragma unroll
        for (int pi = 0; pi < 4; ++pi) {
          const int c = (8 * kh + 2 * pi + hiK) ^ l7;
          short8 vb = *reinterpret_cast<const short8*>(vr + c * 8);
          acc[dg] = __builtin_amdgcn_mfma_f32_32x32x16_bf16(pa[pi], vb, acc[dg], 0, 0, 0);
        }
      }
      __builtin_amdgcn_s_setprio(0);
    }

    // ---- epilogue: merge the two key-halves (r14 verbatim) ----
    const float lw = lsum + __shfl_xor(lsum, 32, 64);
    __syncthreads();                     // all PV done; K/V LDS is dead now
    if (lane < 32) {
      sx[0][kh][headq][lane] = m;
      sx[1][kh][headq][lane] = tmaxh;
      sx[2][kh][headq][lane] = lw;
    }
    __syncthreads();
    const float mo   = sx[0][kh ^ 1][headq][l31];
    const float to   = sx[1][kh ^ 1][headq][l31];
    const float lo2  = sx[2][kh ^ 1][headq][l31];
    const float tmax = fmaxf(tmaxh, to);
    const float fsA  = __expf(m - tmax);          // own-half scale to true max
    const float ltot = lw * fsA + lo2 * __expf(mo - tmax);

    float* mbuf = reinterpret_cast<float*>(&smem[0]);   // 4 heads x 32q x 128d
    if (kh == 1) {
#pragma unroll
      for (int r = 0; r < 16; ++r) {
        const int row = (r & 3) + 8 * (r >> 2) + 4 * hiK;
        const float sfr = __shfl(fsA, row, 64);
#pragma unroll
        for (int dg = 0; dg < 4; ++dg)
          mbuf[headq * 4096 + row * 128 + dg * 32 + l31] = acc[dg][r] * sfr;
      }
    }
    __syncthreads();
    if (kh == 0) {
#pragma unroll
      for (int r = 0; r < 16; ++r) {
        const int row = (r & 3) + 8 * (r >> 2) + 4 * hiK;
        const float sfr = __shfl(fsA, row, 64);
        const size_t ob = ((size_t)(qbase + row) * NH + head) * DD + l31;
#pragma unroll
        for (int dg = 0; dg < 4; ++dg)
          O[ob + dg * 32] = acc[dg][r] * sfr + mbuf[headq * 4096 + row * 128 + dg * 32 + l31];
      }
      if (lane < 32) {
        Mo[(size_t)q * NH + head] = tmax;
        Lo[(size_t)q * NH + head] = ltot;
      }
    }
    __syncthreads();   // mbuf/sx reads done before next job's prologue DMA
  }
}

extern "C" void kernel_launch(void* const* d_in, const int* in_sizes, int n_in,
                              void* d_out, int out_size, void* d_ws, size_t ws_size,
                              hipStream_t stream) {
  const float* Q = (const float*)d_in[0];
  const float* K = (const float*)d_in[1];
  const float* V = (const float*)d_in[2];
  float* O  = (float*)d_out;
  float* Mo = O + (size_t)TT * NH * DD;
  float* Lo = Mo + (size_t)TT * NH;
  short* Kbf  = (short*)d_ws;                          // 4 MB
  short* Vtbf = Kbf + (size_t)NKV * TT * DD;           // 4 MB
  preconv<<<dim3(512), dim3(256), 0, stream>>>(K, V, Kbf, Vtbf);
  attn_fwd<<<dim3(256), dim3(512), 0, stream>>>(Q, Kbf, Vtbf, O, Mo, Lo);
}

// Round 16
// 82.165 us; speedup vs baseline: 1.0057x; 1.0057x over previous
//
#include <hip/hip_runtime.h>
#include <hip/hip_bf16.h>

#define TT  2048
#define NH  32
#define NKV 8
#define DD  128
#define KVB 128         // keys per LDS tile
#define THR 8.0f        // defer-max rescale threshold (T13)

typedef __attribute__((ext_vector_type(8)))  short  short8;
typedef __attribute__((ext_vector_type(4)))  float  f32x4;
typedef __attribute__((ext_vector_type(16))) float  f32x16;
typedef unsigned int u32;
typedef __attribute__((ext_vector_type(4)))  u32    u32x4;

static __device__ __forceinline__ short f2bf(float x) {
  __bf16 b = (__bf16)x;                 // RNE f32->bf16
  return __builtin_bit_cast(short, b);
}
static __device__ __forceinline__ short8 cvt8(f32x4 a, f32x4 b) {
  short8 r;
  r[0]=f2bf(a[0]); r[1]=f2bf(a[1]); r[2]=f2bf(a[2]); r[3]=f2bf(a[3]);
  r[4]=f2bf(b[0]); r[5]=f2bf(b[1]); r[6]=f2bf(b[2]); r[7]=f2bf(b[3]);
  return r;
}
static __device__ __forceinline__ u32 pk2(float lo, float hi) {
  const u32 a = (u32)(unsigned short)f2bf(lo);
  const u32 b = (u32)(unsigned short)f2bf(hi);
  return a | (b << 16);
}
static __device__ __forceinline__ void gload_lds16(const short* g, short* l) {
  __builtin_amdgcn_global_load_lds(
      (const __attribute__((address_space(1))) u32*)g,
      (__attribute__((address_space(3))) u32*)l, 16, 0, 0);
}

// ---------------- pre-pass: K -> bf16 [kvh][j][d]; V -> bf16 transposed [kvh][d][j] ----
__global__ __launch_bounds__(256) void preconv(
    const float* __restrict__ K, const float* __restrict__ V,
    short* __restrict__ Kbf, short* __restrict__ Vtbf)
{
  const int t = threadIdx.x;
  if (blockIdx.x >= 256) {
    const int b  = blockIdx.x - 256;
    const int rr = (b << 6) + (t >> 2);      // rr = j*8+kvh
    const int q  = t & 3;
    const int j = rr >> 3, kvh = rr & 7;
    const float* src = K + (size_t)rr * DD + q * 32;
    short* dst = Kbf + ((size_t)kvh * TT + j) * DD + q * 32;
#pragma unroll
    for (int i = 0; i < 4; ++i) {
      f32x4 a  = *reinterpret_cast<const f32x4*>(src + i * 8);
      f32x4 bb = *reinterpret_cast<const f32x4*>(src + i * 8 + 4);
      *reinterpret_cast<short8*>(dst + i * 8) = cvt8(a, bb);
    }
  } else {
    const int kvh = blockIdx.x >> 5, jt = blockIdx.x & 31;
    __shared__ short Vl[64][136];
    const int jl = t >> 2, q = t & 3;
    const float* src = V + ((size_t)(jt * 64 + jl) * NKV + kvh) * DD + q * 32;
#pragma unroll
    for (int i = 0; i < 4; ++i) {
      f32x4 a  = *reinterpret_cast<const f32x4*>(src + i * 8);
      f32x4 bb = *reinterpret_cast<const f32x4*>(src + i * 8 + 4);
      *reinterpret_cast<short8*>(&Vl[jl][q * 32 + i * 8]) = cvt8(a, bb);
    }
    __syncthreads();
    const int d = t >> 1, jh = t & 1;
    short8 o[4];
#pragma unroll
    for (int k = 0; k < 4; ++k)
#pragma unroll
      for (int i = 0; i < 8; ++i)
        o[k][i] = Vl[jh * 32 + k * 8 + i][d];
    short* dst = Vtbf + ((size_t)kvh * DD + d) * TT + jt * 64 + jh * 32;
#pragma unroll
    for (int k = 0; k < 4; ++k)
      *reinterpret_cast<short8*>(dst + k * 8) = o[k];
  }
}

// ---------------- main attention kernel ------------------------------------------
// r15 structure (passed, perfectly balanced: grid=256 = 1 block/CU, block
// (kvh=bid&7, j=bid>>3) runs heavy strip 63-j then light strip j, EXACTLY 17
// tiles per CU) with the r15 SPILL eliminated:
//   (1) __launch_bounds__(512, 1): LDS (134KB) already forces 1 block/CU =
//       2 waves/EU, so the (512,2) 256-reg unified cap was pure downside --
//       r15 hit it exactly (128 arch + 128 acc) and spilled 9.7MB to scratch
//       (WRITE 33792->43520 KB). Raising the cap removes the spill without
//       any occupancy cost.
//   (2) #pragma unroll 1 on the job loop: prevents the 2x body duplication
//       that inflated live ranges across the unrolled jobs.
// Everything else byte-identical to r15 (which was r14's proven 77.6us body):
// KVB=128, 8 waves = 4 heads x 2 key-halves, defer-max THR=8, DMA after QK^T
// (r13 proved before-QK^T is worse), sx/mbuf epilogue, 16B-chunk XOR swizzle
// (phys = logical ^ (row&7)) pre-applied on the global source address.
// MFMA 32x32x16 layouts: A: lane=A[row=l&31][k=8*(l>>5)+i];
// B: B[k=8*(l>>5)+i][col=l&31]; C/D: col=l&31, row=(reg&3)+8*(reg>>2)+4*(l>>5).
__global__ __launch_bounds__(512, 1) void attn_fwd(
    const float* __restrict__ Q, const short* __restrict__ Kbf,
    const short* __restrict__ Vtbf, float* __restrict__ O,
    float* __restrict__ Mo, float* __restrict__ Lo)
{
  __shared__ __align__(16) short smem[2*KVB*DD + 2*DD*KVB];  // 128KB: Kb | Vt
  __shared__ float sx[3][2][4][32];                          // m / tmax / lsum exchange

  short (*Kb)[KVB][DD] = reinterpret_cast<short(*)[KVB][DD]>(&smem[0]);
  short (*Vt)[DD][KVB] = reinterpret_cast<short(*)[DD][KVB]>(&smem[2*KVB*DD]);

  const int bid  = blockIdx.x;
  const int kvh  = bid & (NKV - 1);          // kvh == XCD id under round-robin
  const int j    = bid >> 3;                 // 0..31
  const int wv   = threadIdx.x >> 6;         // 0..7
  const int headq= wv & 3;
  const int kh   = wv >> 2;                  // key half: keys [64kh, 64kh+64) per tile
  const int lane = threadIdx.x & 63;
  const int l31  = lane & 31;
  const int hiK  = lane >> 5;
  const int l7   = lane & 7;
  const int head = kvh * 4 + headq;

  // ---- staging offsets (job-invariant): K rows and V d-rows [16wv, 16wv+16) ----
  int koff[4], voff[4];
#pragma unroll
  for (int t = 0; t < 4; ++t) {
    const int row = 16 * wv + 4 * t + (lane >> 4);
    const int sw  = (lane & 15) ^ (4 * (t & 1) + (lane >> 4));
    koff[t] = row * DD + sw * 8;
    voff[t] = row * TT + sw * 8;
  }

  const short* kB = Kbf + (size_t)kvh * TT * DD;
  const short* vB = Vtbf + (size_t)kvh * DD * TT;

#pragma unroll 1
  for (int job = 0; job < 2; ++job) {
    const int q32   = (job == 0) ? (63 - j) : j;   // heavy first, then light
    const int qbase = q32 * 32;
    const int q     = qbase + l31;           // this lane's q-column
    const int ntiles = (q32 + 4) >> 2;       // ceil((qbase+32)/128)

    // ---- Q B-frags: lane holds Q[qbase+l31][ks*16 + 8*hiK + i], ks=0..7 ----
    short8 aq[8];
    {
      const float* qp = Q + ((size_t)q * NH + head) * DD + hiK * 8;
#pragma unroll
      for (int ks = 0; ks < 8; ++ks) {
        const float* p = qp + ks * 16;
        aq[ks] = cvt8(*reinterpret_cast<const f32x4*>(p),
                      *reinterpret_cast<const f32x4*>(p + 4));
      }
    }

    f32x16 acc[4];
#pragma unroll
    for (int i = 0; i < 4; ++i) acc[i] = (f32x16)0.0f;
    float m = -INFINITY, tmaxh = -INFINITY, lsum = 0.0f;

    const short* kgp = kB;
    const short* vgp = vB;

    // ---- prologue: DMA tile 0 into buffer 0 ----
#pragma unroll
    for (int t = 0; t < 4; ++t)
      gload_lds16(kgp + koff[t], &Kb[0][16 * wv + 4 * t][0]);
#pragma unroll
    for (int t = 0; t < 4; ++t)
      gload_lds16(vgp + voff[t], &Vt[0][16 * wv + 4 * t][0]);
    kgp += (size_t)KVB * DD;
    vgp += KVB;

    for (int jt = 0; jt < ntiles; ++jt) {
      const int j0  = jt << 7;
      const int buf = jt & 1;

      __syncthreads();   // drains own DMA (vmcnt0); prev buffer free for overwrite

      // ---- QK^T on this wave's 64-key half: st[kg] over keys kh*64+kg*32+[0,32) ----
      f32x16 st[2];
      st[0] = (f32x16)0.0f; st[1] = (f32x16)0.0f;
      __builtin_amdgcn_s_setprio(1);
#pragma unroll
      for (int kg = 0; kg < 2; ++kg) {
        const short* kr = &Kb[buf][kh * 64 + kg * 32 + l31][0];
#pragma unroll
        for (int ks = 0; ks < 8; ++ks) {
          const int c = ((ks << 1) | hiK) ^ l7;
          short8 kb = *reinterpret_cast<const short8*>(kr + c * 8);
          st[kg] = __builtin_amdgcn_mfma_f32_32x32x16_bf16(kb, aq[ks], st[kg], 0, 0, 0);
        }
      }
      __builtin_amdgcn_s_setprio(0);

      // ---- DMA tile jt+1 into buf^1 (r7/r13-proven placement: after QK^T) ----
      if (jt + 1 < ntiles) {
        const int nb = buf ^ 1;
#pragma unroll
        for (int t = 0; t < 4; ++t)
          gload_lds16(kgp + koff[t], &Kb[nb][16 * wv + 4 * t][0]);
#pragma unroll
        for (int t = 0; t < 4; ++t)
          gload_lds16(vgp + voff[t], &Vt[nb][16 * wv + 4 * t][0]);
        kgp += (size_t)KVB * DD;
        vgp += KVB;
      }

      // ---- causal mask: only the last tile can cross the diagonal ----
      if (jt == ntiles - 1) {
#pragma unroll
        for (int kg = 0; kg < 2; ++kg)
#pragma unroll
          for (int r = 0; r < 16; ++r) {
            const int key = j0 + kh * 64 + kg * 32 + (r & 3) + 8 * (r >> 2) + 4 * hiK;
            if (key > q) st[kg][r] = -1.0e10f;
          }
      }

      // ---- half max (lane-local over 64 keys + lane^32 merge) ----
      float mx = fmaxf(st[0][0], st[1][0]);
#pragma unroll
      for (int r = 1; r < 16; ++r) mx = fmaxf(mx, fmaxf(st[0][r], st[1][r]));
      mx = fmaxf(mx, __shfl_xor(mx, 32, 64));
      tmaxh = fmaxf(tmaxh, mx);

      // ---- defer-max: rescale only when the running max grows by >THR ----
      if (__any(mx > m + THR)) {
        const float mn = fmaxf(m, mx);
        const float sc = __expf(m - mn);
        m = mn;
        lsum *= sc;
#pragma unroll
        for (int r = 0; r < 16; ++r) {
          const float sf = __shfl(sc, (r & 3) + 8 * (r >> 2) + 4 * hiK, 64);
          acc[0][r] *= sf; acc[1][r] *= sf; acc[2][r] *= sf; acc[3][r] *= sf;
        }
      }

      // ---- P = exp(S-m); pack to PV A-frags via lane^32 exchange ----
      short8 pa[4];
#pragma unroll
      for (int kg = 0; kg < 2; ++kg) {
        float e[16];
#pragma unroll
        for (int r = 0; r < 16; ++r) e[r] = __expf(st[kg][r] - m);
        lsum += (((e[0]+e[1])+(e[2]+e[3]))+((e[4]+e[5])+(e[6]+e[7])))
              + (((e[8]+e[9])+(e[10]+e[11]))+((e[12]+e[13])+(e[14]+e[15])));
#pragma unroll
        for (int h2 = 0; h2 < 2; ++h2) {
          const int b = 8 * h2;
          u32 u0 = pk2(e[b+0], e[b+1]);
          u32 u1 = pk2(e[b+2], e[b+3]);
          u32 u2 = pk2(e[b+4], e[b+5]);
          u32 u3 = pk2(e[b+6], e[b+7]);
          u32 sA = hiK ? u0 : u2;
          u32 sB = hiK ? u1 : u3;
          u32 rA = __shfl_xor(sA, 32, 64);
          u32 rB = __shfl_xor(sB, 32, 64);
          u32x4 w4;
          w4[0] = hiK ? rA : u0;
          w4[1] = hiK ? rB : u1;
          w4[2] = hiK ? u2 : rA;
          w4[3] = hiK ? u3 : rB;
          pa[kg * 2 + h2] = __builtin_bit_cast(short8, w4);
        }
      }

      // ---- P @ V over this wave's 4 key-slices of 16 (keys kh*64 + 16pi) ----
      __builtin_amdgcn_s_setprio(1);
#pragma unroll
      for (int dg = 0; dg < 4; ++dg) {
        const short* vr = &Vt[buf][dg * 32 + l31][0];
#pragma unroll
        for (int pi = 0; pi < 4; ++pi) {
          const int c = (8 * kh + 2 * pi + hiK) ^ l7;
          short8 vb = *reinterpret_cast<const short8*>(vr + c * 8);
          acc[dg] = __builtin_amdgcn_mfma_f32_32x32x16_bf16(pa[pi], vb, acc[dg], 0, 0, 0);
        }
      }
      __builtin_amdgcn_s_setprio(0);
    }

    // ---- epilogue: merge the two key-halves (r14 verbatim) ----
    const float lw = lsum + __shfl_xor(lsum, 32, 64);
    __syncthreads();                     // all PV done; K/V LDS is dead now
    if (lane < 32) {
      sx[0][kh][headq][lane] = m;
      sx[1][kh][headq][lane] = tmaxh;
      sx[2][kh][headq][lane] = lw;
    }
    __syncthreads();
    const float mo   = sx[0][kh ^ 1][headq][l31];
    const float to   = sx[1][kh ^ 1][headq][l31];
    const float lo2  = sx[2][kh ^ 1][headq][l31];
    const float tmax = fmaxf(tmaxh, to);
    const float fsA  = __expf(m - tmax);          // own-half scale to true max
    const float ltot = lw * fsA + lo2 * __expf(mo - tmax);

    float* mbuf = reinterpret_cast<float*>(&smem[0]);   // 4 heads x 32q x 128d
    if (kh == 1) {
#pragma unroll
      for (int r = 0; r < 16; ++r) {
        const int row = (r & 3) + 8 * (r >> 2) + 4 * hiK;
        const float sfr = __shfl(fsA, row, 64);
#pragma unroll
        for (int dg = 0; dg < 4; ++dg)
          mbuf[headq * 4096 + row * 128 + dg * 32 + l31] = acc[dg][r] * sfr;
      }
    }
    __syncthreads();
    if (kh == 0) {
#pragma unroll
      for (int r = 0; r < 16; ++r) {
        const int row = (r & 3) + 8 * (r >> 2) + 4 * hiK;
        const float sfr = __shfl(fsA, row, 64);
        const size_t ob = ((size_t)(qbase + row) * NH + head) * DD + l31;
#pragma unroll
        for (int dg = 0; dg < 4; ++dg)
          O[ob + dg * 32] = acc[dg][r] * sfr + mbuf[headq * 4096 + row * 128 + dg * 32 + l31];
      }
      if (lane < 32) {
        Mo[(size_t)q * NH + head] = tmax;
        Lo[(size_t)q * NH + head] = ltot;
      }
    }
    __syncthreads();   // mbuf/sx reads done before next job's prologue DMA
  }
}

extern "C" void kernel_launch(void* const* d_in, const int* in_sizes, int n_in,
                              void* d_out, int out_size, void* d_ws, size_t ws_size,
                              hipStream_t stream) {
  const float* Q = (const float*)d_in[0];
  const float* K = (const float*)d_in[1];
  const float* V = (const float*)d_in[2];
  float* O  = (float*)d_out;
  float* Mo = O + (size_t)TT * NH * DD;
  float* Lo = Mo + (size_t)TT * NH;
  short* Kbf  = (short*)d_ws;                          // 4 MB
  short* Vtbf = Kbf + (size_t)NKV * TT * DD;           // 4 MB
  preconv<<<dim3(512), dim3(256), 0, stream>>>(K, V, Kbf, Vtbf);
  attn_fwd<<<dim3(256), dim3(512), 0, stream>>>(Q, Kbf, Vtbf, O, Mo, Lo);
}

// Round 17
// 77.554 us; speedup vs baseline: 1.0655x; 1.0595x over previous
//
#include <hip/hip_runtime.h>
#include <hip/hip_bf16.h>

#define TT  2048
#define NH  32
#define NKV 8
#define DD  128
#define KVB 128         // keys per LDS tile (halves barrier count vs 64)
#define THR 8.0f        // defer-max rescale threshold (T13)

typedef __attribute__((ext_vector_type(8)))  short  short8;
typedef __attribute__((ext_vector_type(4)))  float  f32x4;
typedef __attribute__((ext_vector_type(16))) float  f32x16;
typedef unsigned int u32;
typedef __attribute__((ext_vector_type(4)))  u32    u32x4;

static __device__ __forceinline__ short f2bf(float x) {
  __bf16 b = (__bf16)x;                 // RNE f32->bf16
  return __builtin_bit_cast(short, b);
}
static __device__ __forceinline__ short8 cvt8(f32x4 a, f32x4 b) {
  short8 r;
  r[0]=f2bf(a[0]); r[1]=f2bf(a[1]); r[2]=f2bf(a[2]); r[3]=f2bf(a[3]);
  r[4]=f2bf(b[0]); r[5]=f2bf(b[1]); r[6]=f2bf(b[2]); r[7]=f2bf(b[3]);
  return r;
}
static __device__ __forceinline__ u32 pk2(float lo, float hi) {
  const u32 a = (u32)(unsigned short)f2bf(lo);
  const u32 b = (u32)(unsigned short)f2bf(hi);
  return a | (b << 16);
}
static __device__ __forceinline__ void gload_lds16(const short* g, short* l) {
  __builtin_amdgcn_global_load_lds(
      (const __attribute__((address_space(1))) u32*)g,
      (__attribute__((address_space(3))) u32*)l, 16, 0, 0);
}

// ---------------- pre-pass: K -> bf16 [kvh][j][d]; V -> bf16 transposed [kvh][d][j] ----
__global__ __launch_bounds__(256) void preconv(
    const float* __restrict__ K, const float* __restrict__ V,
    short* __restrict__ Kbf, short* __restrict__ Vtbf)
{
  const int t = threadIdx.x;
  if (blockIdx.x >= 256) {
    const int b  = blockIdx.x - 256;
    const int rr = (b << 6) + (t >> 2);      // rr = j*8+kvh
    const int q  = t & 3;
    const int j = rr >> 3, kvh = rr & 7;
    const float* src = K + (size_t)rr * DD + q * 32;
    short* dst = Kbf + ((size_t)kvh * TT + j) * DD + q * 32;
#pragma unroll
    for (int i = 0; i < 4; ++i) {
      f32x4 a  = *reinterpret_cast<const f32x4*>(src + i * 8);
      f32x4 bb = *reinterpret_cast<const f32x4*>(src + i * 8 + 4);
      *reinterpret_cast<short8*>(dst + i * 8) = cvt8(a, bb);
    }
  } else {
    const int kvh = blockIdx.x >> 5, jt = blockIdx.x & 31;
    __shared__ short Vl[64][136];
    const int jl = t >> 2, q = t & 3;
    const float* src = V + ((size_t)(jt * 64 + jl) * NKV + kvh) * DD + q * 32;
#pragma unroll
    for (int i = 0; i < 4; ++i) {
      f32x4 a  = *reinterpret_cast<const f32x4*>(src + i * 8);
      f32x4 bb = *reinterpret_cast<const f32x4*>(src + i * 8 + 4);
      *reinterpret_cast<short8*>(&Vl[jl][q * 32 + i * 8]) = cvt8(a, bb);
    }
    __syncthreads();
    const int d = t >> 1, jh = t & 1;
    short8 o[4];
#pragma unroll
    for (int k = 0; k < 4; ++k)
#pragma unroll
      for (int i = 0; i < 8; ++i)
        o[k][i] = Vl[jh * 32 + k * 8 + i][d];
    short* dst = Vtbf + ((size_t)kvh * DD + d) * TT + jt * 64 + jh * 32;
#pragma unroll
    for (int k = 0; k < 4; ++k)
      *reinterpret_cast<short8*>(dst + k * 8) = o[k];
  }
}

// ---------------- main attention kernel ------------------------------------------
// SESSION-FINAL: the round-14 kernel verbatim (measured 77.6us, best of session).
// Why this is the close: r15/r16 proved the static-balance rewrite only adds
// register pressure (9.7MB scratch spill regardless of launch_bounds/unroll
// hints) while the r14 grid order -- heavies descending then lights descending --
// is already an LPT queue under the greedy backfill dispatch, so scheduling was
// already near-balanced. Structure: KVB=128 (halves per-strip barrier/drain
// count vs 64 -- r14's win over r7), 8 waves = 4 GQA heads x 2 key-halves,
// independent per-half online softmax with defer-max THR=8, DMA issued AFTER
// QK^T (r13 proved before-QK^T contends with QK^T's ds_reads and is worse),
// sx/mbuf LDS epilogue merge. K/V double-buffered, staged by global_load_lds
// with the 16B-chunk XOR swizzle (phys = logical ^ (row&7)) pre-applied on the
// per-lane GLOBAL source address (LDS dest linear), applied again on reads.
// MFMA 32x32x16 layouts: A: lane=A[row=l&31][k=8*(l>>5)+i];
// B: B[k=8*(l>>5)+i][col=l&31]; C/D: col=l&31, row=(reg&3)+8*(reg>>2)+4*(l>>5).
__global__ __launch_bounds__(512, 2) void attn_fwd(
    const float* __restrict__ Q, const short* __restrict__ Kbf,
    const short* __restrict__ Vtbf, float* __restrict__ O,
    float* __restrict__ Mo, float* __restrict__ Lo)
{
  __shared__ __align__(16) short smem[2*KVB*DD + 2*DD*KVB];  // 128KB: Kb | Vt
  __shared__ float sx[3][2][4][32];                          // m / tmax / lsum exchange

  short (*Kb)[KVB][DD] = reinterpret_cast<short(*)[KVB][DD]>(&smem[0]);
  short (*Vt)[DD][KVB] = reinterpret_cast<short(*)[DD][KVB]>(&smem[2*KVB*DD]);

  const int bid  = blockIdx.x;
  const int kvh  = bid & (NKV - 1);          // kvh == XCD id under round-robin
  const int q32  = 63 - (bid >> 3);          // heavies first, lights after: LPT queue
  const int wv   = threadIdx.x >> 6;         // 0..7
  const int headq= wv & 3;
  const int kh   = wv >> 2;                  // key half: keys [64kh, 64kh+64) per tile
  const int lane = threadIdx.x & 63;
  const int l31  = lane & 31;
  const int hiK  = lane >> 5;
  const int l7   = lane & 7;
  const int head = kvh * 4 + headq;
  const int qbase = q32 * 32;
  const int q    = qbase + l31;              // this lane's q-column

  // ---- staging offsets: wave stages K rows and V d-rows [16wv, 16wv+16) ----
  int koff[4], voff[4];
#pragma unroll
  for (int t = 0; t < 4; ++t) {
    const int row = 16 * wv + 4 * t + (lane >> 4);
    const int sw  = (lane & 15) ^ (4 * (t & 1) + (lane >> 4));
    koff[t] = row * DD + sw * 8;
    voff[t] = row * TT + sw * 8;
  }

  // ---- Q B-frags: lane holds Q[qbase+l31][ks*16 + 8*hiK + i], ks=0..7 ----
  short8 aq[8];
  {
    const float* qp = Q + ((size_t)q * NH + head) * DD + hiK * 8;
#pragma unroll
    for (int ks = 0; ks < 8; ++ks) {
      const float* p = qp + ks * 16;
      aq[ks] = cvt8(*reinterpret_cast<const f32x4*>(p),
                    *reinterpret_cast<const f32x4*>(p + 4));
    }
  }

  f32x16 acc[4];
#pragma unroll
  for (int i = 0; i < 4; ++i) acc[i] = (f32x16)0.0f;
  float m = -INFINITY, tmaxh = -INFINITY, lsum = 0.0f;

  const int ntiles = (q32 + 4) >> 2;   // ceil((qbase+32)/128)

  const short* kgp = Kbf + (size_t)kvh * TT * DD;
  const short* vgp = Vtbf + (size_t)kvh * DD * TT;

  // ---- prologue: DMA tile 0 into buffer 0 ----
#pragma unroll
  for (int t = 0; t < 4; ++t)
    gload_lds16(kgp + koff[t], &Kb[0][16 * wv + 4 * t][0]);
#pragma unroll
  for (int t = 0; t < 4; ++t)
    gload_lds16(vgp + voff[t], &Vt[0][16 * wv + 4 * t][0]);
  kgp += (size_t)KVB * DD;
  vgp += KVB;

  for (int jt = 0; jt < ntiles; ++jt) {
    const int j0  = jt << 7;
    const int buf = jt & 1;

    __syncthreads();   // drains own DMA (vmcnt0); prev buffer free for overwrite

    // ---- QK^T on this wave's 64-key half: st[kg] over keys kh*64+kg*32+[0,32) ----
    f32x16 st[2];
    st[0] = (f32x16)0.0f; st[1] = (f32x16)0.0f;
    __builtin_amdgcn_s_setprio(1);
#pragma unroll
    for (int kg = 0; kg < 2; ++kg) {
      const short* kr = &Kb[buf][kh * 64 + kg * 32 + l31][0];
#pragma unroll
      for (int ks = 0; ks < 8; ++ks) {
        const int c = ((ks << 1) | hiK) ^ l7;
        short8 kb = *reinterpret_cast<const short8*>(kr + c * 8);
        st[kg] = __builtin_amdgcn_mfma_f32_32x32x16_bf16(kb, aq[ks], st[kg], 0, 0, 0);
      }
    }
    __builtin_amdgcn_s_setprio(0);

    // ---- DMA tile jt+1 into buf^1 (r7/r13-proven placement: after QK^T) ----
    if (jt + 1 < ntiles) {
      const int nb = buf ^ 1;
#pragma unroll
      for (int t = 0; t < 4; ++t)
        gload_lds16(kgp + koff[t], &Kb[nb][16 * wv + 4 * t][0]);
#pragma unroll
      for (int t = 0; t < 4; ++t)
        gload_lds16(vgp + voff[t], &Vt[nb][16 * wv + 4 * t][0]);
      kgp += (size_t)KVB * DD;
      vgp += KVB;
    }

    // ---- causal mask: only the last tile can cross the diagonal ----
    if (jt == ntiles - 1) {
#pragma unroll
      for (int kg = 0; kg < 2; ++kg)
#pragma unroll
        for (int r = 0; r < 16; ++r) {
          const int key = j0 + kh * 64 + kg * 32 + (r & 3) + 8 * (r >> 2) + 4 * hiK;
          if (key > q) st[kg][r] = -1.0e10f;
        }
    }

    // ---- half max (lane-local over 64 keys + lane^32 merge) ----
    float mx = fmaxf(st[0][0], st[1][0]);
#pragma unroll
    for (int r = 1; r < 16; ++r) mx = fmaxf(mx, fmaxf(st[0][r], st[1][r]));
    mx = fmaxf(mx, __shfl_xor(mx, 32, 64));
    tmaxh = fmaxf(tmaxh, mx);

    // ---- defer-max: rescale only when the running max grows by >THR ----
    if (__any(mx > m + THR)) {
      const float mn = fmaxf(m, mx);
      const float sc = __expf(m - mn);
      m = mn;
      lsum *= sc;
#pragma unroll
      for (int r = 0; r < 16; ++r) {
        const float sf = __shfl(sc, (r & 3) + 8 * (r >> 2) + 4 * hiK, 64);
        acc[0][r] *= sf; acc[1][r] *= sf; acc[2][r] *= sf; acc[3][r] *= sf;
      }
    }

    // ---- P = exp(S-m); pack to PV A-frags via lane^32 exchange ----
    short8 pa[4];
#pragma unroll
    for (int kg = 0; kg < 2; ++kg) {
      float e[16];
#pragma unroll
      for (int r = 0; r < 16; ++r) e[r] = __expf(st[kg][r] - m);
      lsum += (((e[0]+e[1])+(e[2]+e[3]))+((e[4]+e[5])+(e[6]+e[7])))
            + (((e[8]+e[9])+(e[10]+e[11]))+((e[12]+e[13])+(e[14]+e[15])));
#pragma unroll
      for (int h2 = 0; h2 < 2; ++h2) {
        const int b = 8 * h2;
        u32 u0 = pk2(e[b+0], e[b+1]);
        u32 u1 = pk2(e[b+2], e[b+3]);
        u32 u2 = pk2(e[b+4], e[b+5]);
        u32 u3 = pk2(e[b+6], e[b+7]);
        u32 sA = hiK ? u0 : u2;
        u32 sB = hiK ? u1 : u3;
        u32 rA = __shfl_xor(sA, 32, 64);
        u32 rB = __shfl_xor(sB, 32, 64);
        u32x4 w4;
        w4[0] = hiK ? rA : u0;
        w4[1] = hiK ? rB : u1;
        w4[2] = hiK ? u2 : rA;
        w4[3] = hiK ? u3 : rB;
        pa[kg * 2 + h2] = __builtin_bit_cast(short8, w4);
      }
    }

    // ---- P @ V over this wave's 4 key-slices of 16 (keys kh*64 + 16pi) ----
    __builtin_amdgcn_s_setprio(1);
#pragma unroll
    for (int dg = 0; dg < 4; ++dg) {
      const short* vr = &Vt[buf][dg * 32 + l31][0];
#pragma unroll
      for (int pi = 0; pi < 4; ++pi) {
        const int c = (8 * kh + 2 * pi + hiK) ^ l7;
        short8 vb = *reinterpret_cast<const short8*>(vr + c * 8);
        acc[dg] = __builtin_amdgcn_mfma_f32_32x32x16_bf16(pa[pi], vb, acc[dg], 0, 0, 0);
      }
    }
    __builtin_amdgcn_s_setprio(0);
  }

  // ---- epilogue: merge the two key-halves ----
  const float lw = lsum + __shfl_xor(lsum, 32, 64);
  __syncthreads();                     // all PV done; K/V LDS is dead now
  if (lane < 32) {
    sx[0][kh][headq][lane] = m;
    sx[1][kh][headq][lane] = tmaxh;
    sx[2][kh][headq][lane] = lw;
  }
  __syncthreads();
  const float mo   = sx[0][kh ^ 1][headq][l31];
  const float to   = sx[1][kh ^ 1][headq][l31];
  const float lo2  = sx[2][kh ^ 1][headq][l31];
  const float tmax = fmaxf(tmaxh, to);
  const float fsA  = __expf(m - tmax);          // own-half scale to true max
  const float ltot = lw * fsA + lo2 * __expf(mo - tmax);

  float* mbuf = reinterpret_cast<float*>(&smem[0]);   // 64KB = 4 heads x 32q x 128d
  if (kh == 1) {
#pragma unroll
    for (int r = 0; r < 16; ++r) {
      const int row = (r & 3) + 8 * (r >> 2) + 4 * hiK;
      const float sfr = __shfl(fsA, row, 64);
#pragma unroll
      for (int dg = 0; dg < 4; ++dg)
        mbuf[headq * 4096 + row * 128 + dg * 32 + l31] = acc[dg][r] * sfr;
    }
  }
  __syncthreads();
  if (kh == 0) {
#pragma unroll
    for (int r = 0; r < 16; ++r) {
      const int row = (r & 3) + 8 * (r >> 2) + 4 * hiK;
      const float sfr = __shfl(fsA, row, 64);
      const size_t ob = ((size_t)(qbase + row) * NH + head) * DD + l31;
#pragma unroll
      for (int dg = 0; dg < 4; ++dg)
        O[ob + dg * 32] = acc[dg][r] * sfr + mbuf[headq * 4096 + row * 128 + dg * 32 + l31];
    }
    if (lane < 32) {
      Mo[(size_t)q * NH + head] = tmax;
      Lo[(size_t)q * NH + head] = ltot;
    }
  }
}

extern "C" void kernel_launch(void* const* d_in, const int* in_sizes, int n_in,
                              void* d_out, int out_size, void* d_ws, size_t ws_size,
                              hipStream_t stream) {
  const float* Q = (const float*)d_in[0];
  const float* K = (const float*)d_in[1];
  const float* V = (const float*)d_in[2];
  float* O  = (float*)d_out;
  float* Mo = O + (size_t)TT * NH * DD;
  float* Lo = Mo + (size_t)TT * NH;
  short* Kbf  = (short*)d_ws;                          // 4 MB
  short* Vtbf = Kbf + (size_t)NKV * TT * DD;           // 4 MB
  preconv<<<dim3(512), dim3(256), 0, stream>>>(K, V, Kbf, Vtbf);
  attn_fwd<<<dim3(64 * NKV), dim3(512), 0, stream>>>(Q, Kbf, Vtbf, O, Mo, Lo);
}